// Round 1
// baseline (4388.932 us; speedup 1.0000x reference)
//
#include <hip/hip_runtime.h>

#define NN 4096
#define EE 32768
#define ETOT (EE + NN)
#define HH 8
#define KK 4
#define MM 500
#define GG 2000
#define NEGS 0.2f
#define LNEPS 1e-5f

// ---------- helpers ----------

__device__ __forceinline__ void get_edge(const int* __restrict__ ei, int e, int& s, int& d) {
    if (e < EE) { s = ei[e]; d = ei[EE + e]; }
    else        { s = e - EE; d = e - EE; }   // self-loops appended
}

__device__ __forceinline__ void atomicMaxF(float* addr, float val) {
    // works because every segment sees at least the self-loop value
    if (val >= 0.f) atomicMax((int*)addr, __float_as_int(val));
    else            atomicMin((unsigned int*)addr, __float_as_uint(val));
}

// ---------- CSR build ----------

__global__ void k_zero_i(int* p, int n) {
    int i = blockIdx.x * 256 + threadIdx.x;
    if (i < n) p[i] = 0;
}

__global__ void k_zero_f(float* p, int n) {
    int i = blockIdx.x * 256 + threadIdx.x;
    if (i < n) p[i] = 0.f;
}

__global__ void k_count(const int* __restrict__ ei, int* deg) {
    int e = blockIdx.x * 256 + threadIdx.x;
    if (e < ETOT) { int s, d; get_edge(ei, e, s, d); atomicAdd(&deg[d], 1); }
}

__global__ void k_scan(const int* __restrict__ deg, int* rs, int n) {
    // single block, 1024 threads, 4 items each (n = 4096)
    __shared__ int sums[1024];
    int tid = threadIdx.x;
    int base = tid * 4;
    int loc[4]; int s = 0;
    #pragma unroll
    for (int i = 0; i < 4; i++) {
        int v = (base + i < n) ? deg[base + i] : 0;
        loc[i] = s; s += v;
    }
    sums[tid] = s;
    __syncthreads();
    for (int off = 1; off < 1024; off <<= 1) {
        int v = (tid >= off) ? sums[tid - off] : 0;
        __syncthreads();
        sums[tid] += v;
        __syncthreads();
    }
    int prev = (tid > 0) ? sums[tid - 1] : 0;
    #pragma unroll
    for (int i = 0; i < 4; i++)
        if (base + i < n) rs[base + i] = prev + loc[i];
    if (tid == 1023) rs[n] = sums[1023];
}

__global__ void k_fill(const int* __restrict__ ei, const int* __restrict__ rs,
                       int* cur, int* csr_src, int* csr_eid) {
    int e = blockIdx.x * 256 + threadIdx.x;
    if (e < ETOT) {
        int s, d; get_edge(ei, e, s, d);
        int pos = rs[d] + atomicAdd(&cur[d], 1);
        csr_src[pos] = s;
        csr_eid[pos] = e;
    }
}

// ---------- GEMM: C[M,N] = A[M,K] * B[K,N]; M = 4096 (grid.y*64) ----------

__global__ __launch_bounds__(256) void k_gemm(
    const float* __restrict__ A, const float* __restrict__ B, float* __restrict__ C,
    int N, int Kd, int lda, int ldb, int ldc,
    long long strideB, long long strideC) {
    __shared__ float As[16][65];   // +1 pad: transposed store
    __shared__ float Bs[16][64];
    const float* Bp = B + (size_t)blockIdx.z * strideB;
    float* Cp = C + (size_t)blockIdx.z * strideC;
    int row0 = blockIdx.y * 64, col0 = blockIdx.x * 64;
    int tid = threadIdx.x;
    int tx = tid & 15, ty = tid >> 4;
    float acc[4][4];
    #pragma unroll
    for (int i = 0; i < 4; i++)
        #pragma unroll
        for (int j = 0; j < 4; j++) acc[i][j] = 0.f;

    for (int k0 = 0; k0 < Kd; k0 += 16) {
        #pragma unroll
        for (int i = tid; i < 1024; i += 256) {
            int r = i >> 4, c = i & 15;
            As[c][r] = A[(size_t)(row0 + r) * lda + k0 + c];
        }
        #pragma unroll
        for (int i = tid; i < 1024; i += 256) {
            int r = i >> 6, c = i & 63;
            int col = col0 + c;
            Bs[r][c] = (col < N) ? Bp[(size_t)(k0 + r) * ldb + col] : 0.f;
        }
        __syncthreads();
        #pragma unroll
        for (int kk = 0; kk < 16; kk++) {
            float av[4], bv[4];
            #pragma unroll
            for (int i = 0; i < 4; i++) av[i] = As[kk][ty * 4 + i];
            #pragma unroll
            for (int j = 0; j < 4; j++) bv[j] = Bs[kk][tx * 4 + j];
            #pragma unroll
            for (int i = 0; i < 4; i++)
                #pragma unroll
                for (int j = 0; j < 4; j++) acc[i][j] += av[i] * bv[j];
        }
        __syncthreads();
    }
    #pragma unroll
    for (int i = 0; i < 4; i++) {
        int r = row0 + ty * 4 + i;
        #pragma unroll
        for (int j = 0; j < 4; j++) {
            int col = col0 + tx * 4 + j;
            if (col < N) Cp[(size_t)r * ldc + col] = acc[i][j];
        }
    }
}

// ---------- per-(node,head) attention dots ----------

__global__ void k_sd(const float* __restrict__ xp, const float* __restrict__ as_,
                     const float* __restrict__ ad_, float* s, float* d, int H, int C) {
    int n = blockIdx.x / H, h = blockIdx.x % H;
    int lane = threadIdx.x;
    const float* row = xp + (size_t)n * H * C + (size_t)h * C;
    const float* av = as_ + (size_t)h * C;
    const float* bv = ad_ + (size_t)h * C;
    float ss = 0.f, dd = 0.f;
    for (int c = lane; c < C; c += 64) {
        float x = row[c];
        ss += x * av[c];
        dd += x * bv[c];
    }
    #pragma unroll
    for (int o = 32; o > 0; o >>= 1) {
        ss += __shfl_down(ss, o, 64);
        dd += __shfl_down(dd, o, 64);
    }
    if (lane == 0) { s[n * H + h] = ss; d[n * H + h] = dd; }
}

// ---------- edge softmax ----------

__global__ void k_init_mz(float* m, float* z, int n) {
    int i = blockIdx.x * 256 + threadIdx.x;
    if (i < n) { m[i] = -__builtin_inff(); z[i] = 0.f; }
}

__global__ void k_edge_max(const int* __restrict__ ei, const float* __restrict__ s,
                           const float* __restrict__ d, float* ew, float* m,
                           int H, int total) {
    int i = blockIdx.x * 256 + threadIdx.x;
    if (i >= total) return;
    int e = i / H, h = i - e * H;
    int sn, dn; get_edge(ei, e, sn, dn);
    float v = s[sn * H + h] + d[dn * H + h];
    v = (v >= 0.f) ? v : NEGS * v;   // leaky_relu
    ew[i] = v;
    atomicMaxF(&m[dn * H + h], v);
}

__global__ void k_edge_sum(const int* __restrict__ ei, float* ew,
                           const float* __restrict__ m, float* z, int H, int total) {
    int i = blockIdx.x * 256 + threadIdx.x;
    if (i >= total) return;
    int e = i / H, h = i - e * H;
    int sn, dn; get_edge(ei, e, sn, dn);
    float p = expf(ew[i] - m[dn * H + h]);
    ew[i] = p;
    atomicAdd(&z[dn * H + h], p);
}

// ---------- aggregation (layers 1-3): out = relu(sum alpha*xp[src] + bias) ----------

__global__ __launch_bounds__(256) void k_agg(
    const float* __restrict__ xp, const float* __restrict__ p, const float* __restrict__ z,
    const int* __restrict__ csr_src, const int* __restrict__ csr_eid,
    const int* __restrict__ rs, const float* __restrict__ bias,
    float* out, int H, int C) {
    __shared__ int sh_src[256];
    __shared__ int sh_eid[256];
    __shared__ float sh_w[256 * HH];
    int n = blockIdx.x, tid = threadIdx.x;
    int Dout = H * C;
    int start = rs[n], end = rs[n + 1];
    float acc[16];
    #pragma unroll
    for (int i = 0; i < 16; i++) acc[i] = 0.f;

    for (int e0 = start; e0 < end; e0 += 256) {
        int cnt = min(256, end - e0);
        if (tid < cnt) { sh_src[tid] = csr_src[e0 + tid]; sh_eid[tid] = csr_eid[e0 + tid]; }
        __syncthreads();
        for (int i = tid; i < cnt * H; i += 256)
            sh_w[i] = p[sh_eid[i / H] * H + (i % H)];
        __syncthreads();
        int ci = 0;
        for (int c = tid; c < Dout; c += 256, ci++) {
            int h = c / C;
            float a = acc[ci];
            for (int i = 0; i < cnt; i++)
                a += sh_w[i * H + h] * xp[(size_t)sh_src[i] * Dout + c];
            acc[ci] = a;
        }
        __syncthreads();
    }
    int ci = 0;
    for (int c = tid; c < Dout; c += 256, ci++) {
        int h = c / C;
        float v = acc[ci] / (z[n * H + h] + 1e-16f) + bias[c];
        out[(size_t)n * Dout + c] = fmaxf(v, 0.f);
    }
}

// ---------- LayerNorm (in-place) ----------

__global__ __launch_bounds__(256) void k_ln(float* buf, const float* __restrict__ g,
                                            const float* __restrict__ b, int Dout) {
    __shared__ float red[256];
    int n = blockIdx.x, tid = threadIdx.x;
    float* row = buf + (size_t)n * Dout;
    float s = 0.f;
    for (int c = tid; c < Dout; c += 256) s += row[c];
    red[tid] = s; __syncthreads();
    for (int o = 128; o > 0; o >>= 1) { if (tid < o) red[tid] += red[tid + o]; __syncthreads(); }
    float mu = red[0] / Dout;
    __syncthreads();
    float v = 0.f;
    for (int c = tid; c < Dout; c += 256) { float d = row[c] - mu; v += d * d; }
    red[tid] = v; __syncthreads();
    for (int o = 128; o > 0; o >>= 1) { if (tid < o) red[tid] += red[tid + o]; __syncthreads(); }
    float rstd = rsqrtf(red[0] / Dout + LNEPS);
    for (int c = tid; c < Dout; c += 256)
        row[c] = (row[c] - mu) * rstd * g[c] + b[c];
}

// ---------- head aggregation: writes per_head and idx-scattered full ----------

__global__ __launch_bounds__(256) void k_agg_head(
    const float* __restrict__ xp, const float* __restrict__ p, const float* __restrict__ z,
    const int* __restrict__ csr_src, const int* __restrict__ csr_eid,
    const int* __restrict__ rs, const float* __restrict__ bias,
    const int* __restrict__ idxm, float* out_full, float* out_ph) {
    __shared__ int sh_src[256];
    __shared__ int sh_eid[256];
    __shared__ float sh_w[256 * KK];
    int n = blockIdx.x, tid = threadIdx.x;
    const int Dout = KK * MM;   // 2000
    int start = rs[n], end = rs[n + 1];
    float acc[8];
    #pragma unroll
    for (int i = 0; i < 8; i++) acc[i] = 0.f;

    for (int e0 = start; e0 < end; e0 += 256) {
        int cnt = min(256, end - e0);
        if (tid < cnt) { sh_src[tid] = csr_src[e0 + tid]; sh_eid[tid] = csr_eid[e0 + tid]; }
        __syncthreads();
        for (int i = tid; i < cnt * KK; i += 256)
            sh_w[i] = p[sh_eid[i / KK] * KK + (i % KK)];
        __syncthreads();
        int ci = 0;
        for (int c = tid; c < Dout; c += 256, ci++) {
            int k = c / MM;
            float a = acc[ci];
            for (int i = 0; i < cnt; i++)
                a += sh_w[i * KK + k] * xp[(size_t)sh_src[i] * Dout + c];
            acc[ci] = a;
        }
        __syncthreads();
    }
    int ci = 0;
    for (int c = tid; c < Dout; c += 256, ci++) {
        int k = c / MM, m = c - k * MM;
        float v = acc[ci] / (z[n * KK + k] + 1e-16f) + bias[c];
        out_ph[((size_t)k * NN + n) * MM + m] = v;
        out_full[(size_t)n * GG + idxm[c]] = v;
    }
}

// ---------- host launcher ----------

extern "C" void kernel_launch(void* const* d_in, const int* in_sizes, int n_in,
                              void* d_out, int out_size, void* d_ws, size_t ws_size,
                              hipStream_t stream) {
    (void)in_sizes; (void)n_in; (void)out_size; (void)ws_size;
    const float* x   = (const float*)d_in[0];
    const int*   ei  = (const int*)d_in[1];
    const float* W1  = (const float*)d_in[2];
    const float* as1 = (const float*)d_in[3];
    const float* ad1 = (const float*)d_in[4];
    const float* b1  = (const float*)d_in[5];
    const float* g1  = (const float*)d_in[6];
    const float* be1 = (const float*)d_in[7];
    const float* W2  = (const float*)d_in[8];
    const float* as2 = (const float*)d_in[9];
    const float* ad2 = (const float*)d_in[10];
    const float* b2  = (const float*)d_in[11];
    const float* g2  = (const float*)d_in[12];
    const float* be2 = (const float*)d_in[13];
    const float* W3  = (const float*)d_in[14];
    const float* as3 = (const float*)d_in[15];
    const float* ad3 = (const float*)d_in[16];
    const float* b3  = (const float*)d_in[17];
    const float* g3  = (const float*)d_in[18];
    const float* be3 = (const float*)d_in[19];
    const float* Wh  = (const float*)d_in[20];
    const float* ash = (const float*)d_in[21];
    const float* adh = (const float*)d_in[22];
    const float* bh  = (const float*)d_in[23];
    const int*   idxm = (const int*)d_in[24];
    float* out = (float*)d_out;

    // workspace carve
    char* w = (char*)d_ws;
    auto carve = [&](size_t bytes) { char* p = w; w += (bytes + 255) & ~(size_t)255; return p; };
    float* bufA    = (float*)carve((size_t)NN * 3584 * 4);   // xp buffer (max Dout=3584)
    float* sarr    = (float*)carve((size_t)NN * HH * 4);
    float* darr    = (float*)carve((size_t)NN * HH * 4);
    float* marr    = (float*)carve((size_t)NN * HH * 4);
    float* zarr    = (float*)carve((size_t)NN * HH * 4);
    float* ework   = (float*)carve((size_t)ETOT * HH * 4);
    int*   csr_src = (int*)carve((size_t)ETOT * 4);
    int*   csr_eid = (int*)carve((size_t)ETOT * 4);
    int*   rowst   = (int*)carve((size_t)(NN + 1) * 4);
    int*   cur     = (int*)carve((size_t)NN * 4);
    // h-buffer lives in d_out (16.38M floats >= 14.68M needed); dead before final writes
    float* bufB = out;

    // ---- CSR build ----
    k_zero_i<<<(NN + 255) / 256, 256, 0, stream>>>(cur, NN);
    k_count<<<(ETOT + 255) / 256, 256, 0, stream>>>(ei, cur);
    k_scan<<<1, 1024, 0, stream>>>(cur, rowst, NN);
    k_zero_i<<<(NN + 255) / 256, 256, 0, stream>>>(cur, NN);
    k_fill<<<(ETOT + 255) / 256, 256, 0, stream>>>(ei, rowst, cur, csr_src, csr_eid);

    // ---- GAT layer runner (layers 1-3: relu + LN) ----
    auto gat = [&](const float* hin, const float* W, const float* as_, const float* ad_,
                   const float* bias, const float* gam, const float* bet, int Din, int C) {
        int Dout = HH * C;
        dim3 gg((Dout + 63) / 64, NN / 64, 1);
        k_gemm<<<gg, 256, 0, stream>>>(hin, W, bufA, Dout, Din, Din, Dout, Dout, 0, 0);
        k_sd<<<NN * HH, 64, 0, stream>>>(bufA, as_, ad_, sarr, darr, HH, C);
        k_init_mz<<<(NN * HH + 255) / 256, 256, 0, stream>>>(marr, zarr, NN * HH);
        int tot = ETOT * HH;
        k_edge_max<<<(tot + 255) / 256, 256, 0, stream>>>(ei, sarr, darr, ework, marr, HH, tot);
        k_edge_sum<<<(tot + 255) / 256, 256, 0, stream>>>(ei, ework, marr, zarr, HH, tot);
        k_agg<<<NN, 256, 0, stream>>>(bufA, ework, zarr, csr_src, csr_eid, rowst, bias, bufB, HH, C);
        k_ln<<<NN, 256, 0, stream>>>(bufB, gam, bet, Dout);
    };
    gat(x,    W1, as1, ad1, b1, g1, be1, 256,  448);
    gat(bufB, W2, as2, ad2, b2, g2, be2, 3584, 384);
    gat(bufB, W3, as3, ad3, b3, g3, be3, 3072, 256);

    // ---- head stage: K=4 single-head GATs treated as H=4 heads ----
    dim3 gh((MM + 63) / 64, NN / 64, KK);
    k_gemm<<<gh, 256, 0, stream>>>(bufB, Wh, bufA, MM, 2048, 2048, MM, GG,
                                   (long long)2048 * MM, (long long)MM);
    k_sd<<<NN * KK, 64, 0, stream>>>(bufA, ash, adh, sarr, darr, KK, MM);
    k_init_mz<<<(NN * KK + 255) / 256, 256, 0, stream>>>(marr, zarr, NN * KK);
    int tot = ETOT * KK;
    k_edge_max<<<(tot + 255) / 256, 256, 0, stream>>>(ei, sarr, darr, ework, marr, KK, tot);
    k_edge_sum<<<(tot + 255) / 256, 256, 0, stream>>>(ei, ework, marr, zarr, KK, tot);
    // zero the 'full' output region (idx is a permutation, but be safe), then scatter
    k_zero_f<<<(NN * GG + 255) / 256, 256, 0, stream>>>(out, NN * GG);
    k_agg_head<<<NN, 256, 0, stream>>>(bufA, ework, zarr, csr_src, csr_eid, rowst,
                                       bh, idxm, out, out + (size_t)NN * GG);
}

// Round 3
// 1598.761 us; speedup vs baseline: 2.7452x; 2.7452x over previous
//
#include <hip/hip_runtime.h>

#define NN 4096
#define EE 32768
#define ETOT (EE + NN)
#define HH 8
#define KK 4
#define MM 500
#define GG 2000
#define NEGS 0.2f
#define LNEPS 1e-5f

typedef unsigned short ushort;
typedef __attribute__((ext_vector_type(8))) short short8;
typedef __attribute__((ext_vector_type(4))) float floatx4;

// ---------- helpers ----------

__device__ __forceinline__ void get_edge(const int* __restrict__ ei, int e, int& s, int& d) {
    if (e < EE) { s = ei[e]; d = ei[EE + e]; }
    else        { s = e - EE; d = e - EE; }   // self-loops appended
}

__device__ __forceinline__ void atomicMaxF(float* addr, float val) {
    if (val >= 0.f) atomicMax((int*)addr, __float_as_int(val));
    else            atomicMin((unsigned int*)addr, __float_as_uint(val));
}

__device__ __forceinline__ ushort f2b(float x) {   // fp32 -> bf16 RNE
    unsigned u = __float_as_uint(x);
    return (ushort)((u + 0x7FFFu + ((u >> 16) & 1u)) >> 16);
}

__device__ __forceinline__ float b2f(ushort h) {
    return __uint_as_float(((unsigned)h) << 16);
}

// split v into hi+lo bf16 (hi = bf16(v), lo = bf16(v - hi))
__device__ __forceinline__ void splitbf(float v, ushort& hi, ushort& lo) {
    hi = f2b(v);
    lo = f2b(v - b2f(hi));
}

// async global->LDS, 16 bytes/lane; LDS dest = wave-uniform base + lane*16
__device__ __forceinline__ void async_lds16(const ushort* g, ushort* l) {
    __builtin_amdgcn_global_load_lds(
        (const __attribute__((address_space(1))) unsigned int*)(const void*)g,
        (__attribute__((address_space(3))) unsigned int*)(void*)l,
        16, 0, 0);
}

// ---------- CSR build ----------

__global__ void k_zero_i(int* p, int n) {
    int i = blockIdx.x * 256 + threadIdx.x;
    if (i < n) p[i] = 0;
}

__global__ void k_zero_f(float* p, int n) {
    int i = blockIdx.x * 256 + threadIdx.x;
    if (i < n) p[i] = 0.f;
}

__global__ void k_count(const int* __restrict__ ei, int* deg) {
    int e = blockIdx.x * 256 + threadIdx.x;
    if (e < ETOT) { int s, d; get_edge(ei, e, s, d); atomicAdd(&deg[d], 1); }
}

__global__ void k_scan(const int* __restrict__ deg, int* rs, int n) {
    __shared__ int sums[1024];
    int tid = threadIdx.x;
    int base = tid * 4;
    int loc[4]; int s = 0;
    #pragma unroll
    for (int i = 0; i < 4; i++) {
        int v = (base + i < n) ? deg[base + i] : 0;
        loc[i] = s; s += v;
    }
    sums[tid] = s;
    __syncthreads();
    for (int off = 1; off < 1024; off <<= 1) {
        int v = (tid >= off) ? sums[tid - off] : 0;
        __syncthreads();
        sums[tid] += v;
        __syncthreads();
    }
    int prev = (tid > 0) ? sums[tid - 1] : 0;
    #pragma unroll
    for (int i = 0; i < 4; i++)
        if (base + i < n) rs[base + i] = prev + loc[i];
    if (tid == 1023) rs[n] = sums[1023];
}

__global__ void k_fill(const int* __restrict__ ei, const int* __restrict__ rs,
                       int* cur, int* csr_src, int* csr_eid) {
    int e = blockIdx.x * 256 + threadIdx.x;
    if (e < ETOT) {
        int s, d; get_edge(ei, e, s, d);
        int pos = rs[d] + atomicAdd(&cur[d], 1);
        csr_src[pos] = s;
        csr_eid[pos] = e;
    }
}

// ---------- fp32 -> split bf16 elementwise (for x) ----------

__global__ void k_f2b2(const float* __restrict__ in, ushort* __restrict__ hi,
                       ushort* __restrict__ lo, int n) {
    int i = blockIdx.x * 256 + threadIdx.x;
    if (i < n) { ushort h, l; splitbf(in[i], h, l); hi[i] = h; lo[i] = l; }
}

// ---------- weight transpose + split bf16: W[K][ldw] fp32 -> Wt[Npad][K] bf16 x2 ----------

__global__ __launch_bounds__(256) void k_wt(const float* __restrict__ W,
                                            ushort* __restrict__ WtH, ushort* __restrict__ WtL,
                                            int Kd, int Nvalid, int ldw,
                                            long long sW, long long sWt) {
    __shared__ float t[32][33];
    const float* Wp = W + (size_t)blockIdx.z * sW;
    ushort* WtHp = WtH + (size_t)blockIdx.z * sWt;
    ushort* WtLp = WtL + (size_t)blockIdx.z * sWt;
    int n0 = blockIdx.x * 32, k0 = blockIdx.y * 32;
    int tx = threadIdx.x & 31, ty = threadIdx.x >> 5;   // ty 0..7
    #pragma unroll
    for (int i = 0; i < 32; i += 8)
        t[ty + i][tx] = (n0 + tx < Nvalid) ? Wp[(size_t)(k0 + ty + i) * ldw + n0 + tx] : 0.f;
    __syncthreads();
    #pragma unroll
    for (int i = 0; i < 32; i += 8) {
        ushort h, l; splitbf(t[tx][ty + i], h, l);
        WtHp[(size_t)(n0 + ty + i) * Kd + k0 + tx] = h;
        WtLp[(size_t)(n0 + ty + i) * Kd + k0 + tx] = l;
    }
}

// ---------- split-bf16 MFMA GEMM: C = A * Bt^T, fp32-equivalent accuracy ----------
// 128x128 tile, BK=32; 4 LDS tiles (A_hi, A_lo, B_hi, B_lo) = 32 KB.
// acc += Ah*Bh + Al*Bh + Ah*Bl  (lo*lo dropped, O(eps^2))

#define BM 128
#define BN 128
#define BK 32

__global__ __launch_bounds__(256) void k_gemm_mfma(
    const ushort* __restrict__ Ah, const ushort* __restrict__ Al,   // [M][Kd] bf16
    const ushort* __restrict__ BtH, const ushort* __restrict__ BtL, // [Npad][Kd] bf16
    float* __restrict__ C,
    int Kd, int Nreal, int ldc,
    long long strideBt, long long strideC)
{
    __shared__ __align__(16) ushort AsH[BM * BK];
    __shared__ __align__(16) ushort AsL[BM * BK];
    __shared__ __align__(16) ushort BsH[BN * BK];
    __shared__ __align__(16) ushort BsL[BN * BK];

    const ushort* BtHp = BtH + (size_t)blockIdx.z * strideBt;
    const ushort* BtLp = BtL + (size_t)blockIdx.z * strideBt;
    float* Cp = C + (size_t)blockIdx.z * strideC;
    int col0 = blockIdx.x * BN, row0 = blockIdx.y * BM;

    int lane = threadIdx.x & 63;
    int wave = threadIdx.x >> 6;
    int wm = (wave >> 1) * 64, wn = (wave & 1) * 64;

    // staging: wave covers 32 rows of each tile; 16 rows (64B each) per call
    int srow = wave * 32 + (lane >> 2);
    int schunk = (lane & 3) * 8;
    const ushort* gah = Ah  + (size_t)(row0 + srow) * Kd + schunk;
    const ushort* gal = Al  + (size_t)(row0 + srow) * Kd + schunk;
    const ushort* gbh = BtHp + (size_t)(col0 + srow) * Kd + schunk;
    const ushort* gbl = BtLp + (size_t)(col0 + srow) * Kd + schunk;
    ushort* lAh = &AsH[(wave * 32) * BK];
    ushort* lAl = &AsL[(wave * 32) * BK];
    ushort* lBh = &BsH[(wave * 32) * BK];
    ushort* lBl = &BsL[(wave * 32) * BK];

    int r = lane & 15;
    int q = (lane >> 4) * 8;

    floatx4 acc[4][4];
    #pragma unroll
    for (int i = 0; i < 4; i++)
        #pragma unroll
        for (int j = 0; j < 4; j++) acc[i][j] = (floatx4){0.f, 0.f, 0.f, 0.f};

    for (int k0 = 0; k0 < Kd; k0 += BK) {
        #pragma unroll
        for (int c = 0; c < 2; c++) {
            async_lds16(gah + k0 + (size_t)(c * 16) * Kd, lAh + (c * 16) * BK);
            async_lds16(gal + k0 + (size_t)(c * 16) * Kd, lAl + (c * 16) * BK);
            async_lds16(gbh + k0 + (size_t)(c * 16) * Kd, lBh + (c * 16) * BK);
            async_lds16(gbl + k0 + (size_t)(c * 16) * Kd, lBl + (c * 16) * BK);
        }
        __syncthreads();
        short8 ah[4], al[4], bh[4], bl[4];
        #pragma unroll
        for (int i = 0; i < 4; i++) {
            ah[i] = *(const short8*)&AsH[(wm + i * 16 + r) * BK + q];
            al[i] = *(const short8*)&AsL[(wm + i * 16 + r) * BK + q];
        }
        #pragma unroll
        for (int j = 0; j < 4; j++) {
            bh[j] = *(const short8*)&BsH[(wn + j * 16 + r) * BK + q];
            bl[j] = *(const short8*)&BsL[(wn + j * 16 + r) * BK + q];
        }
        #pragma unroll
        for (int i = 0; i < 4; i++)
            #pragma unroll
            for (int j = 0; j < 4; j++) {
                acc[i][j] = __builtin_amdgcn_mfma_f32_16x16x32_bf16(ah[i], bh[j], acc[i][j], 0, 0, 0);
                acc[i][j] = __builtin_amdgcn_mfma_f32_16x16x32_bf16(al[i], bh[j], acc[i][j], 0, 0, 0);
                acc[i][j] = __builtin_amdgcn_mfma_f32_16x16x32_bf16(ah[i], bl[j], acc[i][j], 0, 0, 0);
            }
        __syncthreads();
    }

    int q4 = (lane >> 4) * 4;
    #pragma unroll
    for (int i = 0; i < 4; i++) {
        #pragma unroll
        for (int rr = 0; rr < 4; rr++) {
            int row = row0 + wm + i * 16 + q4 + rr;
            #pragma unroll
            for (int j = 0; j < 4; j++) {
                int col = col0 + wn + j * 16 + (lane & 15);
                if (col < Nreal) Cp[(size_t)row * ldc + col] = acc[i][j][rr];
            }
        }
    }
}

// ---------- per-(node,head) attention dots ----------

__global__ void k_sd(const float* __restrict__ xp, const float* __restrict__ as_,
                     const float* __restrict__ ad_, float* s, float* d, int H, int C) {
    int n = blockIdx.x / H, h = blockIdx.x % H;
    int lane = threadIdx.x;
    const float* row = xp + (size_t)n * H * C + (size_t)h * C;
    const float* av = as_ + (size_t)h * C;
    const float* bv = ad_ + (size_t)h * C;
    float ss = 0.f, dd = 0.f;
    for (int c = lane; c < C; c += 64) {
        float x = row[c];
        ss += x * av[c];
        dd += x * bv[c];
    }
    #pragma unroll
    for (int o = 32; o > 0; o >>= 1) {
        ss += __shfl_down(ss, o, 64);
        dd += __shfl_down(dd, o, 64);
    }
    if (lane == 0) { s[n * H + h] = ss; d[n * H + h] = dd; }
}

// ---------- edge softmax ----------

__global__ void k_init_mz(float* m, float* z, int n) {
    int i = blockIdx.x * 256 + threadIdx.x;
    if (i < n) { m[i] = -__builtin_inff(); z[i] = 0.f; }
}

__global__ void k_edge_max(const int* __restrict__ ei, const float* __restrict__ s,
                           const float* __restrict__ d, float* ew, float* m,
                           int H, int total) {
    int i = blockIdx.x * 256 + threadIdx.x;
    if (i >= total) return;
    int e = i / H, h = i - e * H;
    int sn, dn; get_edge(ei, e, sn, dn);
    float v = s[sn * H + h] + d[dn * H + h];
    v = (v >= 0.f) ? v : NEGS * v;   // leaky_relu
    ew[i] = v;
    atomicMaxF(&m[dn * H + h], v);
}

__global__ void k_edge_sum(const int* __restrict__ ei, float* ew,
                           const float* __restrict__ m, float* z, int H, int total) {
    int i = blockIdx.x * 256 + threadIdx.x;
    if (i >= total) return;
    int e = i / H, h = i - e * H;
    int sn, dn; get_edge(ei, e, sn, dn);
    float p = expf(ew[i] - m[dn * H + h]);
    ew[i] = p;
    atomicAdd(&z[dn * H + h], p);
}

// ---------- aggregation + ReLU + LayerNorm fused; writes split-bf16 h ----------

__global__ __launch_bounds__(256) void k_agg_ln(
    const float* __restrict__ xp, const float* __restrict__ p, const float* __restrict__ z,
    const int* __restrict__ csr_src, const int* __restrict__ csr_eid,
    const int* __restrict__ rs, const float* __restrict__ bias,
    const float* __restrict__ gam, const float* __restrict__ bet,
    ushort* __restrict__ outH, ushort* __restrict__ outL, int H, int C) {
    __shared__ int sh_src[256];
    __shared__ int sh_eid[256];
    __shared__ float sh_w[256 * HH];
    __shared__ float red[256];
    __shared__ float red2[256];
    int n = blockIdx.x, tid = threadIdx.x;
    int Dout = H * C;
    int start = rs[n], end = rs[n + 1];
    float acc[16];
    #pragma unroll
    for (int i = 0; i < 16; i++) acc[i] = 0.f;

    for (int e0 = start; e0 < end; e0 += 256) {
        int cnt = min(256, end - e0);
        if (tid < cnt) { sh_src[tid] = csr_src[e0 + tid]; sh_eid[tid] = csr_eid[e0 + tid]; }
        __syncthreads();
        for (int i = tid; i < cnt * H; i += 256)
            sh_w[i] = p[sh_eid[i / H] * H + (i % H)];
        __syncthreads();
        int ci = 0;
        for (int c = tid; c < Dout; c += 256, ci++) {
            int h = c / C;
            float a = acc[ci];
            for (int i = 0; i < cnt; i++)
                a += sh_w[i * H + h] * xp[(size_t)sh_src[i] * Dout + c];
            acc[ci] = a;
        }
        __syncthreads();
    }

    // ReLU + LayerNorm in-register
    float vals[16];
    float sum = 0.f, sumsq = 0.f;
    int ci = 0;
    for (int c = tid; c < Dout; c += 256, ci++) {
        int h = c / C;
        float v = acc[ci] / (z[n * H + h] + 1e-16f) + bias[c];
        v = fmaxf(v, 0.f);
        vals[ci] = v;
        sum += v; sumsq += v * v;
    }
    red[tid] = sum; red2[tid] = sumsq;
    __syncthreads();
    for (int o = 128; o > 0; o >>= 1) {
        if (tid < o) { red[tid] += red[tid + o]; red2[tid] += red2[tid + o]; }
        __syncthreads();
    }
    float mu = red[0] / Dout;
    float var = red2[0] / Dout - mu * mu;
    float rstd = rsqrtf(var + LNEPS);
    ci = 0;
    for (int c = tid; c < Dout; c += 256, ci++) {
        float y = (vals[ci] - mu) * rstd * gam[c] + bet[c];
        ushort h, l; splitbf(y, h, l);
        outH[(size_t)n * Dout + c] = h;
        outL[(size_t)n * Dout + c] = l;
    }
}

// ---------- head aggregation: writes per_head and idx-scattered full ----------

__global__ __launch_bounds__(256) void k_agg_head(
    const float* __restrict__ xp, const float* __restrict__ p, const float* __restrict__ z,
    const int* __restrict__ csr_src, const int* __restrict__ csr_eid,
    const int* __restrict__ rs, const float* __restrict__ bias,
    const int* __restrict__ idxm, float* out_full, float* out_ph) {
    __shared__ int sh_src[256];
    __shared__ int sh_eid[256];
    __shared__ float sh_w[256 * KK];
    int n = blockIdx.x, tid = threadIdx.x;
    const int Dout = KK * MM;   // 2000
    int start = rs[n], end = rs[n + 1];
    float acc[8];
    #pragma unroll
    for (int i = 0; i < 8; i++) acc[i] = 0.f;

    for (int e0 = start; e0 < end; e0 += 256) {
        int cnt = min(256, end - e0);
        if (tid < cnt) { sh_src[tid] = csr_src[e0 + tid]; sh_eid[tid] = csr_eid[e0 + tid]; }
        __syncthreads();
        for (int i = tid; i < cnt * KK; i += 256)
            sh_w[i] = p[sh_eid[i / KK] * KK + (i % KK)];
        __syncthreads();
        int ci = 0;
        for (int c = tid; c < Dout; c += 256, ci++) {
            int k = c / MM;
            float a = acc[ci];
            for (int i = 0; i < cnt; i++)
                a += sh_w[i * KK + k] * xp[(size_t)sh_src[i] * Dout + c];
            acc[ci] = a;
        }
        __syncthreads();
    }
    int ci = 0;
    for (int c = tid; c < Dout; c += 256, ci++) {
        int k = c / MM, m = c - k * MM;
        float v = acc[ci] / (z[n * KK + k] + 1e-16f) + bias[c];
        out_ph[((size_t)k * NN + n) * MM + m] = v;
        out_full[(size_t)n * GG + idxm[c]] = v;
    }
}

// ---------- host launcher ----------

extern "C" void kernel_launch(void* const* d_in, const int* in_sizes, int n_in,
                              void* d_out, int out_size, void* d_ws, size_t ws_size,
                              hipStream_t stream) {
    (void)in_sizes; (void)n_in; (void)out_size; (void)ws_size;
    const float* x   = (const float*)d_in[0];
    const int*   ei  = (const int*)d_in[1];
    const float* W1  = (const float*)d_in[2];
    const float* as1 = (const float*)d_in[3];
    const float* ad1 = (const float*)d_in[4];
    const float* b1  = (const float*)d_in[5];
    const float* g1  = (const float*)d_in[6];
    const float* be1 = (const float*)d_in[7];
    const float* W2  = (const float*)d_in[8];
    const float* as2 = (const float*)d_in[9];
    const float* ad2 = (const float*)d_in[10];
    const float* b2  = (const float*)d_in[11];
    const float* g2  = (const float*)d_in[12];
    const float* be2 = (const float*)d_in[13];
    const float* W3  = (const float*)d_in[14];
    const float* as3 = (const float*)d_in[15];
    const float* ad3 = (const float*)d_in[16];
    const float* b3  = (const float*)d_in[17];
    const float* g3  = (const float*)d_in[18];
    const float* be3 = (const float*)d_in[19];
    const float* Wh  = (const float*)d_in[20];
    const float* ash = (const float*)d_in[21];
    const float* adh = (const float*)d_in[22];
    const float* bh  = (const float*)d_in[23];
    const int*   idxm = (const int*)d_in[24];
    float* out = (float*)d_out;

    // workspace carve (~86 MB)
    char* w = (char*)d_ws;
    auto carve = [&](size_t bytes) { char* p = w; w += (bytes + 255) & ~(size_t)255; return p; };
    float*  bufA    = (float*)carve((size_t)NN * 3584 * 4);            // xp fp32
    ushort* WtH     = (ushort*)carve((size_t)1792 * 3584 * 2);         // transposed weights hi
    ushort* WtL     = (ushort*)carve((size_t)1792 * 3584 * 2);         // transposed weights lo
    float*  sarr    = (float*)carve((size_t)NN * HH * 4);
    float*  darr    = (float*)carve((size_t)NN * HH * 4);
    float*  marr    = (float*)carve((size_t)NN * HH * 4);
    float*  zarr    = (float*)carve((size_t)NN * HH * 4);
    float*  ework   = (float*)carve((size_t)ETOT * HH * 4);
    int*    csr_src = (int*)carve((size_t)ETOT * 4);
    int*    csr_eid = (int*)carve((size_t)ETOT * 4);
    int*    rowst   = (int*)carve((size_t)(NN + 1) * 4);
    int*    cur     = (int*)carve((size_t)NN * 4);
    // split-bf16 activations live in d_out (58.7 MB <= 65.5 MB; dead before final writes)
    ushort* Ahi = (ushort*)d_out;
    ushort* Alo = Ahi + (size_t)NN * 3584;

    // ---- CSR build ----
    k_zero_i<<<(NN + 255) / 256, 256, 0, stream>>>(cur, NN);
    k_count<<<(ETOT + 255) / 256, 256, 0, stream>>>(ei, cur);
    k_scan<<<1, 1024, 0, stream>>>(cur, rowst, NN);
    k_zero_i<<<(NN + 255) / 256, 256, 0, stream>>>(cur, NN);
    k_fill<<<(ETOT + 255) / 256, 256, 0, stream>>>(ei, rowst, cur, csr_src, csr_eid);

    // ---- x -> split bf16 ----
    k_f2b2<<<(NN * 256 + 255) / 256, 256, 0, stream>>>(x, Ahi, Alo, NN * 256);

    // ---- GAT layer runner (layers 1-3) ----
    auto gat = [&](const float* W, const float* as_, const float* ad_,
                   const float* bias, const float* gam, const float* bet, int Din, int C) {
        int Dout = HH * C;
        // chunked over output columns so Wt fits in its carve
        for (int c0 = 0; c0 < Dout; c0 += 1792) {
            int cn = min(1792, Dout - c0);
            k_wt<<<dim3(cn / 32, Din / 32, 1), 256, 0, stream>>>(
                W + c0, WtH, WtL, Din, cn, Dout, 0, 0);
            k_gemm_mfma<<<dim3(cn / BN, NN / BM, 1), 256, 0, stream>>>(
                Ahi, Alo, WtH, WtL, bufA + c0, Din, cn, Dout, 0, 0);
        }
        k_sd<<<NN * HH, 64, 0, stream>>>(bufA, as_, ad_, sarr, darr, HH, C);
        k_init_mz<<<(NN * HH + 255) / 256, 256, 0, stream>>>(marr, zarr, NN * HH);
        int tot = ETOT * HH;
        k_edge_max<<<(tot + 255) / 256, 256, 0, stream>>>(ei, sarr, darr, ework, marr, HH, tot);
        k_edge_sum<<<(tot + 255) / 256, 256, 0, stream>>>(ei, ework, marr, zarr, HH, tot);
        k_agg_ln<<<NN, 256, 0, stream>>>(bufA, ework, zarr, csr_src, csr_eid, rowst,
                                         bias, gam, bet, Ahi, Alo, HH, C);
    };
    gat(W1, as1, ad1, b1, g1, be1, 256,  448);
    gat(W2, as2, ad2, b2, g2, be2, 3584, 384);
    gat(W3, as3, ad3, b3, g3, be3, 3072, 256);

    // ---- head stage: K=4 single-head GATs as batched GEMM + 4-head attention ----
    k_wt<<<dim3(512 / 32, 2048 / 32, KK), 256, 0, stream>>>(
        Wh, WtH, WtL, 2048, MM, MM, (long long)2048 * MM, (long long)512 * 2048);
    k_gemm_mfma<<<dim3(512 / BN, NN / BM, KK), 256, 0, stream>>>(
        Ahi, Alo, WtH, WtL, bufA, 2048, MM, GG, (long long)512 * 2048, (long long)MM);
    k_sd<<<NN * KK, 64, 0, stream>>>(bufA, ash, adh, sarr, darr, KK, MM);
    k_init_mz<<<(NN * KK + 255) / 256, 256, 0, stream>>>(marr, zarr, NN * KK);
    int tot = ETOT * KK;
    k_edge_max<<<(tot + 255) / 256, 256, 0, stream>>>(ei, sarr, darr, ework, marr, KK, tot);
    k_edge_sum<<<(tot + 255) / 256, 256, 0, stream>>>(ei, ework, marr, zarr, KK, tot);
    k_zero_f<<<(NN * GG + 255) / 256, 256, 0, stream>>>(out, NN * GG);
    k_agg_head<<<NN, 256, 0, stream>>>(bufA, ework, zarr, csr_src, csr_eid, rowst,
                                       bh, idxm, out, out + (size_t)NN * GG);
}

// Round 4
// 1126.383 us; speedup vs baseline: 3.8965x; 1.4194x over previous
//
#include <hip/hip_runtime.h>

#define NN 4096
#define EE 32768
#define ETOT (EE + NN)
#define HH 8
#define KK 4
#define MM 500
#define GG 2000
#define NEGS 0.2f
#define LNEPS 1e-5f

typedef unsigned short ushort;
typedef _Float16 half_t;
typedef __attribute__((ext_vector_type(8))) _Float16 half8;
typedef __attribute__((ext_vector_type(4))) float floatx4;

// ---------- helpers ----------

__device__ __forceinline__ void get_edge(const int* __restrict__ ei, int e, int& s, int& d) {
    if (e < EE) { s = ei[e]; d = ei[EE + e]; }
    else        { s = e - EE; d = e - EE; }   // self-loops appended
}

__device__ __forceinline__ void atomicMaxF(float* addr, float val) {
    if (val >= 0.f) atomicMax((int*)addr, __float_as_int(val));
    else            atomicMin((unsigned int*)addr, __float_as_uint(val));
}

__device__ __forceinline__ half_t f2h(float x) { return (half_t)x; }  // RNE

// async global->LDS, 16 bytes/lane; LDS dest = wave-uniform base + lane*16
__device__ __forceinline__ void async_lds16(const half_t* g, half_t* l) {
    __builtin_amdgcn_global_load_lds(
        (const __attribute__((address_space(1))) unsigned int*)(const void*)g,
        (__attribute__((address_space(3))) unsigned int*)(void*)l,
        16, 0, 0);
}

// ---------- CSR build ----------

__global__ void k_zero_i(int* p, int n) {
    int i = blockIdx.x * 256 + threadIdx.x;
    if (i < n) p[i] = 0;
}

__global__ void k_zero_f(float* p, int n) {
    int i = blockIdx.x * 256 + threadIdx.x;
    if (i < n) p[i] = 0.f;
}

__global__ void k_count(const int* __restrict__ ei, int* deg) {
    int e = blockIdx.x * 256 + threadIdx.x;
    if (e < ETOT) { int s, d; get_edge(ei, e, s, d); atomicAdd(&deg[d], 1); }
}

__global__ void k_scan(const int* __restrict__ deg, int* rs, int n) {
    __shared__ int sums[1024];
    int tid = threadIdx.x;
    int base = tid * 4;
    int loc[4]; int s = 0;
    #pragma unroll
    for (int i = 0; i < 4; i++) {
        int v = (base + i < n) ? deg[base + i] : 0;
        loc[i] = s; s += v;
    }
    sums[tid] = s;
    __syncthreads();
    for (int off = 1; off < 1024; off <<= 1) {
        int v = (tid >= off) ? sums[tid - off] : 0;
        __syncthreads();
        sums[tid] += v;
        __syncthreads();
    }
    int prev = (tid > 0) ? sums[tid - 1] : 0;
    #pragma unroll
    for (int i = 0; i < 4; i++)
        if (base + i < n) rs[base + i] = prev + loc[i];
    if (tid == 1023) rs[n] = sums[1023];
}

__global__ void k_fill(const int* __restrict__ ei, const int* __restrict__ rs,
                       int* cur, int* csr_src, int* csr_eid) {
    int e = blockIdx.x * 256 + threadIdx.x;
    if (e < ETOT) {
        int s, d; get_edge(ei, e, s, d);
        int pos = rs[d] + atomicAdd(&cur[d], 1);
        csr_src[pos] = s;
        csr_eid[pos] = e;
    }
}

// ---------- fp32 -> fp16 elementwise (for x) ----------

__global__ void k_f2h(const float* __restrict__ in, half_t* __restrict__ out, int n) {
    int i = blockIdx.x * 256 + threadIdx.x;
    if (i < n) out[i] = f2h(in[i]);
}

// ---------- weight transpose + fp16: W[K][ldw] fp32 -> Wt[Npad][K] fp16 ----------

__global__ __launch_bounds__(256) void k_wt(const float* __restrict__ W,
                                            half_t* __restrict__ Wt,
                                            int Kd, int Nvalid, int ldw,
                                            long long sW, long long sWt) {
    __shared__ float t[32][33];
    const float* Wp = W + (size_t)blockIdx.z * sW;
    half_t* Wtp = Wt + (size_t)blockIdx.z * sWt;
    int n0 = blockIdx.x * 32, k0 = blockIdx.y * 32;
    int tx = threadIdx.x & 31, ty = threadIdx.x >> 5;   // ty 0..7
    #pragma unroll
    for (int i = 0; i < 32; i += 8)
        t[ty + i][tx] = (n0 + tx < Nvalid) ? Wp[(size_t)(k0 + ty + i) * ldw + n0 + tx] : 0.f;
    __syncthreads();
    #pragma unroll
    for (int i = 0; i < 32; i += 8)
        Wtp[(size_t)(n0 + ty + i) * Kd + k0 + tx] = f2h(t[tx][ty + i]);
}

// ---------- fp16 MFMA GEMM: C[M][ldc] = A[M][Kd] * Bt[Npad][Kd]^T ----------
// 128x128 tile, BK=64, 4 waves each computing a 64x64 sub-tile of 4x4 mfma frags.

#define BM 128
#define BN 128
#define BK 64

__global__ __launch_bounds__(256) void k_gemm_mfma(
    const half_t* __restrict__ A,    // [M][Kd] fp16
    const half_t* __restrict__ Bt,   // [Npad][Kd] fp16 (B transposed)
    float* __restrict__ C,
    int Kd, int Nreal, int ldc,
    long long strideBt, long long strideC)
{
    __shared__ __align__(16) half_t As[BM * BK];
    __shared__ __align__(16) half_t Bs[BN * BK];

    const half_t* Btp = Bt + (size_t)blockIdx.z * strideBt;
    float* Cp = C + (size_t)blockIdx.z * strideC;
    int col0 = blockIdx.x * BN, row0 = blockIdx.y * BM;

    int lane = threadIdx.x & 63;
    int wave = threadIdx.x >> 6;
    int wm = (wave >> 1) * 64, wn = (wave & 1) * 64;

    // staging addressing: wave covers 32 rows of each tile, 8 rows per call
    int srow = wave * 32 + (lane >> 3);        // relative tile row for this lane
    int schunk = (lane & 7) * 8;               // fp16 elements within row
    const half_t* ga = A  + (size_t)(row0 + srow) * Kd + schunk;
    const half_t* gb = Btp + (size_t)(col0 + srow) * Kd + schunk;
    half_t* lA = &As[(wave * 32) * BK];
    half_t* lB = &Bs[(wave * 32) * BK];

    int r = lane & 15;
    int q = (lane >> 4) * 8;

    floatx4 acc[4][4];
    #pragma unroll
    for (int i = 0; i < 4; i++)
        #pragma unroll
        for (int j = 0; j < 4; j++) acc[i][j] = (floatx4){0.f, 0.f, 0.f, 0.f};

    for (int k0 = 0; k0 < Kd; k0 += BK) {
        #pragma unroll
        for (int j = 0; j < 4; j++) {
            async_lds16(ga + k0 + (size_t)(j * 8) * Kd, lA + (j * 8) * BK);
            async_lds16(gb + k0 + (size_t)(j * 8) * Kd, lB + (j * 8) * BK);
        }
        __syncthreads();
        #pragma unroll
        for (int kk = 0; kk < BK; kk += 32) {
            half8 a[4], b[4];
            #pragma unroll
            for (int i = 0; i < 4; i++)
                a[i] = *(const half8*)&As[(wm + i * 16 + r) * BK + kk + q];
            #pragma unroll
            for (int j = 0; j < 4; j++)
                b[j] = *(const half8*)&Bs[(wn + j * 16 + r) * BK + kk + q];
            #pragma unroll
            for (int i = 0; i < 4; i++)
                #pragma unroll
                for (int j = 0; j < 4; j++)
                    acc[i][j] = __builtin_amdgcn_mfma_f32_16x16x32_f16(a[i], b[j], acc[i][j], 0, 0, 0);
        }
        __syncthreads();
    }

    int q4 = (lane >> 4) * 4;
    #pragma unroll
    for (int i = 0; i < 4; i++) {
        #pragma unroll
        for (int rr = 0; rr < 4; rr++) {
            int row = row0 + wm + i * 16 + q4 + rr;
            #pragma unroll
            for (int j = 0; j < 4; j++) {
                int col = col0 + wn + j * 16 + (lane & 15);
                if (col < Nreal) Cp[(size_t)row * ldc + col] = acc[i][j][rr];
            }
        }
    }
}

// ---------- per-(node,head) attention dots ----------

__global__ void k_sd(const float* __restrict__ xp, const float* __restrict__ as_,
                     const float* __restrict__ ad_, float* s, float* d, int H, int C) {
    int n = blockIdx.x / H, h = blockIdx.x % H;
    int lane = threadIdx.x;
    const float* row = xp + (size_t)n * H * C + (size_t)h * C;
    const float* av = as_ + (size_t)h * C;
    const float* bv = ad_ + (size_t)h * C;
    float ss = 0.f, dd = 0.f;
    for (int c = lane; c < C; c += 64) {
        float x = row[c];
        ss += x * av[c];
        dd += x * bv[c];
    }
    #pragma unroll
    for (int o = 32; o > 0; o >>= 1) {
        ss += __shfl_down(ss, o, 64);
        dd += __shfl_down(dd, o, 64);
    }
    if (lane == 0) { s[n * H + h] = ss; d[n * H + h] = dd; }
}

// ---------- edge softmax ----------

__global__ void k_init_mz(float* m, float* z, int n) {
    int i = blockIdx.x * 256 + threadIdx.x;
    if (i < n) { m[i] = -__builtin_inff(); z[i] = 0.f; }
}

__global__ void k_edge_max(const int* __restrict__ ei, const float* __restrict__ s,
                           const float* __restrict__ d, float* ew, float* m,
                           int H, int total) {
    int i = blockIdx.x * 256 + threadIdx.x;
    if (i >= total) return;
    int e = i / H, h = i - e * H;
    int sn, dn; get_edge(ei, e, sn, dn);
    float v = s[sn * H + h] + d[dn * H + h];
    v = (v >= 0.f) ? v : NEGS * v;   // leaky_relu
    ew[i] = v;
    atomicMaxF(&m[dn * H + h], v);
}

__global__ void k_edge_sum(const int* __restrict__ ei, float* ew,
                           const float* __restrict__ m, float* z, int H, int total) {
    int i = blockIdx.x * 256 + threadIdx.x;
    if (i >= total) return;
    int e = i / H, h = i - e * H;
    int sn, dn; get_edge(ei, e, sn, dn);
    float p = expf(ew[i] - m[dn * H + h]);
    ew[i] = p;
    atomicAdd(&z[dn * H + h], p);
}

// ---------- aggregation + ReLU + LayerNorm fused; writes fp16 h ----------

__global__ __launch_bounds__(256) void k_agg_ln(
    const float* __restrict__ xp, const float* __restrict__ p, const float* __restrict__ z,
    const int* __restrict__ csr_src, const int* __restrict__ csr_eid,
    const int* __restrict__ rs, const float* __restrict__ bias,
    const float* __restrict__ gam, const float* __restrict__ bet,
    half_t* __restrict__ outh, int H, int C) {
    __shared__ int sh_src[256];
    __shared__ int sh_eid[256];
    __shared__ float sh_w[256 * HH];
    __shared__ float red[256];
    __shared__ float red2[256];
    int n = blockIdx.x, tid = threadIdx.x;
    int Dout = H * C;
    int start = rs[n], end = rs[n + 1];
    float acc[16];
    #pragma unroll
    for (int i = 0; i < 16; i++) acc[i] = 0.f;

    for (int e0 = start; e0 < end; e0 += 256) {
        int cnt = min(256, end - e0);
        if (tid < cnt) { sh_src[tid] = csr_src[e0 + tid]; sh_eid[tid] = csr_eid[e0 + tid]; }
        __syncthreads();
        for (int i = tid; i < cnt * H; i += 256)
            sh_w[i] = p[sh_eid[i / H] * H + (i % H)];
        __syncthreads();
        int ci = 0;
        for (int c = tid; c < Dout; c += 256, ci++) {
            int h = c / C;
            float a = acc[ci];
            for (int i = 0; i < cnt; i++)
                a += sh_w[i * H + h] * xp[(size_t)sh_src[i] * Dout + c];
            acc[ci] = a;
        }
        __syncthreads();
    }

    // ReLU + LayerNorm in-register
    float vals[16];
    float sum = 0.f, sumsq = 0.f;
    int ci = 0;
    for (int c = tid; c < Dout; c += 256, ci++) {
        int h = c / C;
        float v = acc[ci] / (z[n * H + h] + 1e-16f) + bias[c];
        v = fmaxf(v, 0.f);
        vals[ci] = v;
        sum += v; sumsq += v * v;
    }
    red[tid] = sum; red2[tid] = sumsq;
    __syncthreads();
    for (int o = 128; o > 0; o >>= 1) {
        if (tid < o) { red[tid] += red[tid + o]; red2[tid] += red2[tid + o]; }
        __syncthreads();
    }
    float mu = red[0] / Dout;
    float var = red2[0] / Dout - mu * mu;
    float rstd = rsqrtf(var + LNEPS);
    ci = 0;
    for (int c = tid; c < Dout; c += 256, ci++)
        outh[(size_t)n * Dout + c] = f2h((vals[ci] - mu) * rstd * gam[c] + bet[c]);
}

// ---------- head aggregation: writes per_head and idx-scattered full ----------

__global__ __launch_bounds__(256) void k_agg_head(
    const float* __restrict__ xp, const float* __restrict__ p, const float* __restrict__ z,
    const int* __restrict__ csr_src, const int* __restrict__ csr_eid,
    const int* __restrict__ rs, const float* __restrict__ bias,
    const int* __restrict__ idxm, float* out_full, float* out_ph) {
    __shared__ int sh_src[256];
    __shared__ int sh_eid[256];
    __shared__ float sh_w[256 * KK];
    int n = blockIdx.x, tid = threadIdx.x;
    const int Dout = KK * MM;   // 2000
    int start = rs[n], end = rs[n + 1];
    float acc[8];
    #pragma unroll
    for (int i = 0; i < 8; i++) acc[i] = 0.f;

    for (int e0 = start; e0 < end; e0 += 256) {
        int cnt = min(256, end - e0);
        if (tid < cnt) { sh_src[tid] = csr_src[e0 + tid]; sh_eid[tid] = csr_eid[e0 + tid]; }
        __syncthreads();
        for (int i = tid; i < cnt * KK; i += 256)
            sh_w[i] = p[sh_eid[i / KK] * KK + (i % KK)];
        __syncthreads();
        int ci = 0;
        for (int c = tid; c < Dout; c += 256, ci++) {
            int k = c / MM;
            float a = acc[ci];
            for (int i = 0; i < cnt; i++)
                a += sh_w[i * KK + k] * xp[(size_t)sh_src[i] * Dout + c];
            acc[ci] = a;
        }
        __syncthreads();
    }
    int ci = 0;
    for (int c = tid; c < Dout; c += 256, ci++) {
        int k = c / MM, m = c - k * MM;
        float v = acc[ci] / (z[n * KK + k] + 1e-16f) + bias[c];
        out_ph[((size_t)k * NN + n) * MM + m] = v;
        out_full[(size_t)n * GG + idxm[c]] = v;
    }
}

// ---------- host launcher ----------

extern "C" void kernel_launch(void* const* d_in, const int* in_sizes, int n_in,
                              void* d_out, int out_size, void* d_ws, size_t ws_size,
                              hipStream_t stream) {
    (void)in_sizes; (void)n_in; (void)out_size; (void)ws_size;
    const float* x   = (const float*)d_in[0];
    const int*   ei  = (const int*)d_in[1];
    const float* W1  = (const float*)d_in[2];
    const float* as1 = (const float*)d_in[3];
    const float* ad1 = (const float*)d_in[4];
    const float* b1  = (const float*)d_in[5];
    const float* g1  = (const float*)d_in[6];
    const float* be1 = (const float*)d_in[7];
    const float* W2  = (const float*)d_in[8];
    const float* as2 = (const float*)d_in[9];
    const float* ad2 = (const float*)d_in[10];
    const float* b2  = (const float*)d_in[11];
    const float* g2  = (const float*)d_in[12];
    const float* be2 = (const float*)d_in[13];
    const float* W3  = (const float*)d_in[14];
    const float* as3 = (const float*)d_in[15];
    const float* ad3 = (const float*)d_in[16];
    const float* b3  = (const float*)d_in[17];
    const float* g3  = (const float*)d_in[18];
    const float* be3 = (const float*)d_in[19];
    const float* Wh  = (const float*)d_in[20];
    const float* ash = (const float*)d_in[21];
    const float* adh = (const float*)d_in[22];
    const float* bh  = (const float*)d_in[23];
    const int*   idxm = (const int*)d_in[24];
    float* out = (float*)d_out;

    // workspace carve (~85 MB)
    char* w = (char*)d_ws;
    auto carve = [&](size_t bytes) { char* p = w; w += (bytes + 255) & ~(size_t)255; return p; };
    float*  bufA    = (float*)carve((size_t)NN * 3584 * 4);            // xp fp32
    half_t* Wt      = (half_t*)carve((size_t)3072 * 3584 * 2);         // transposed fp16 weights (max: W2)
    float*  sarr    = (float*)carve((size_t)NN * HH * 4);
    float*  darr    = (float*)carve((size_t)NN * HH * 4);
    float*  marr    = (float*)carve((size_t)NN * HH * 4);
    float*  zarr    = (float*)carve((size_t)NN * HH * 4);
    float*  ework   = (float*)carve((size_t)ETOT * HH * 4);
    int*    csr_src = (int*)carve((size_t)ETOT * 4);
    int*    csr_eid = (int*)carve((size_t)ETOT * 4);
    int*    rowst   = (int*)carve((size_t)(NN + 1) * 4);
    int*    cur     = (int*)carve((size_t)NN * 4);
    // fp16 activations live in d_out (29.4 MB <= 65.5 MB; dead before final writes)
    half_t* Ah = (half_t*)d_out;

    // ---- CSR build ----
    k_zero_i<<<(NN + 255) / 256, 256, 0, stream>>>(cur, NN);
    k_count<<<(ETOT + 255) / 256, 256, 0, stream>>>(ei, cur);
    k_scan<<<1, 1024, 0, stream>>>(cur, rowst, NN);
    k_zero_i<<<(NN + 255) / 256, 256, 0, stream>>>(cur, NN);
    k_fill<<<(ETOT + 255) / 256, 256, 0, stream>>>(ei, rowst, cur, csr_src, csr_eid);

    // ---- x -> fp16 ----
    k_f2h<<<(NN * 256 + 255) / 256, 256, 0, stream>>>(x, Ah, NN * 256);

    // ---- GAT layer runner (layers 1-3) ----
    auto gat = [&](const float* W, const float* as_, const float* ad_,
                   const float* bias, const float* gam, const float* bet, int Din, int C) {
        int Dout = HH * C;
        k_wt<<<dim3(Dout / 32, Din / 32, 1), 256, 0, stream>>>(W, Wt, Din, Dout, Dout, 0, 0);
        k_gemm_mfma<<<dim3(Dout / BN, NN / BM, 1), 256, 0, stream>>>(
            Ah, Wt, bufA, Din, Dout, Dout, 0, 0);
        k_sd<<<NN * HH, 64, 0, stream>>>(bufA, as_, ad_, sarr, darr, HH, C);
        k_init_mz<<<(NN * HH + 255) / 256, 256, 0, stream>>>(marr, zarr, NN * HH);
        int tot = ETOT * HH;
        k_edge_max<<<(tot + 255) / 256, 256, 0, stream>>>(ei, sarr, darr, ework, marr, HH, tot);
        k_edge_sum<<<(tot + 255) / 256, 256, 0, stream>>>(ei, ework, marr, zarr, HH, tot);
        k_agg_ln<<<NN, 256, 0, stream>>>(bufA, ework, zarr, csr_src, csr_eid, rowst,
                                         bias, gam, bet, Ah, HH, C);
    };
    gat(W1, as1, ad1, b1, g1, be1, 256,  448);
    gat(W2, as2, ad2, b2, g2, be2, 3584, 384);
    gat(W3, as3, ad3, b3, g3, be3, 3072, 256);

    // ---- head stage: K=4 single-head GATs as batched GEMM + 4-head attention ----
    k_wt<<<dim3(512 / 32, 2048 / 32, KK), 256, 0, stream>>>(
        Wh, Wt, 2048, MM, MM, (long long)2048 * MM, (long long)512 * 2048);
    k_gemm_mfma<<<dim3(512 / BN, NN / BM, KK), 256, 0, stream>>>(
        Ah, Wt, bufA, 2048, MM, GG, (long long)512 * 2048, (long long)MM);
    k_sd<<<NN * KK, 64, 0, stream>>>(bufA, ash, adh, sarr, darr, KK, MM);
    k_init_mz<<<(NN * KK + 255) / 256, 256, 0, stream>>>(marr, zarr, NN * KK);
    int tot = ETOT * KK;
    k_edge_max<<<(tot + 255) / 256, 256, 0, stream>>>(ei, sarr, darr, ework, marr, KK, tot);
    k_edge_sum<<<(tot + 255) / 256, 256, 0, stream>>>(ei, ework, marr, zarr, KK, tot);
    k_zero_f<<<(NN * GG + 255) / 256, 256, 0, stream>>>(out, NN * GG);
    k_agg_head<<<NN, 256, 0, stream>>>(bufA, ework, zarr, csr_src, csr_eid, rowst,
                                       bh, idxm, out, out + (size_t)NN * GG);
}

// Round 5
// 708.556 us; speedup vs baseline: 6.1942x; 1.5897x over previous
//
#include <hip/hip_runtime.h>

#define NN 4096
#define EE 32768
#define ETOT (EE + NN)
#define HH 8
#define KK 4
#define MM 500
#define GG 2000
#define NEGS 0.2f
#define LNEPS 1e-5f

typedef unsigned short ushort;
typedef _Float16 half_t;
typedef __attribute__((ext_vector_type(8))) _Float16 half8;
typedef __attribute__((ext_vector_type(4))) float floatx4;

// ---------- helpers ----------

__device__ __forceinline__ void get_edge(const int* __restrict__ ei, int e, int& s, int& d) {
    if (e < EE) { s = ei[e]; d = ei[EE + e]; }
    else        { s = e - EE; d = e - EE; }   // self-loops appended
}

__device__ __forceinline__ void atomicMaxF(float* addr, float val) {
    if (val >= 0.f) atomicMax((int*)addr, __float_as_int(val));
    else            atomicMin((unsigned int*)addr, __float_as_uint(val));
}

__device__ __forceinline__ half_t f2h(float x) { return (half_t)x; }  // RNE

// async global->LDS, 16 bytes/lane; LDS dest = wave-uniform base + lane*16
__device__ __forceinline__ void async_lds16(const half_t* g, half_t* l) {
    __builtin_amdgcn_global_load_lds(
        (const __attribute__((address_space(1))) unsigned int*)(const void*)g,
        (__attribute__((address_space(3))) unsigned int*)(void*)l,
        16, 0, 0);
}

// ---------- CSR build ----------

__global__ void k_zero_i(int* p, int n) {
    int i = blockIdx.x * 256 + threadIdx.x;
    if (i < n) p[i] = 0;
}

__global__ void k_zero_f(float* p, int n) {
    int i = blockIdx.x * 256 + threadIdx.x;
    if (i < n) p[i] = 0.f;
}

__global__ void k_count(const int* __restrict__ ei, int* deg) {
    int e = blockIdx.x * 256 + threadIdx.x;
    if (e < ETOT) { int s, d; get_edge(ei, e, s, d); atomicAdd(&deg[d], 1); }
}

__global__ void k_scan(const int* __restrict__ deg, int* rs, int n) {
    __shared__ int sums[1024];
    int tid = threadIdx.x;
    int base = tid * 4;
    int loc[4]; int s = 0;
    #pragma unroll
    for (int i = 0; i < 4; i++) {
        int v = (base + i < n) ? deg[base + i] : 0;
        loc[i] = s; s += v;
    }
    sums[tid] = s;
    __syncthreads();
    for (int off = 1; off < 1024; off <<= 1) {
        int v = (tid >= off) ? sums[tid - off] : 0;
        __syncthreads();
        sums[tid] += v;
        __syncthreads();
    }
    int prev = (tid > 0) ? sums[tid - 1] : 0;
    #pragma unroll
    for (int i = 0; i < 4; i++)
        if (base + i < n) rs[base + i] = prev + loc[i];
    if (tid == 1023) rs[n] = sums[1023];
}

__global__ void k_fill(const int* __restrict__ ei, const int* __restrict__ rs,
                       int* cur, int* csr_src, int* csr_eid) {
    int e = blockIdx.x * 256 + threadIdx.x;
    if (e < ETOT) {
        int s, d; get_edge(ei, e, s, d);
        int pos = rs[d] + atomicAdd(&cur[d], 1);
        csr_src[pos] = s;
        csr_eid[pos] = e;
    }
}

// ---------- fp32 -> fp16 elementwise (for x) ----------

__global__ void k_f2h(const float* __restrict__ in, half_t* __restrict__ out, int n) {
    int i = blockIdx.x * 256 + threadIdx.x;
    if (i < n) out[i] = f2h(in[i]);
}

// ---------- weight transpose + fp16: W[K][ldw] fp32 -> Wt[Npad][K] fp16 ----------

__global__ __launch_bounds__(256) void k_wt(const float* __restrict__ W,
                                            half_t* __restrict__ Wt,
                                            int Kd, int Nvalid, int ldw,
                                            long long sW, long long sWt) {
    __shared__ float t[32][33];
    const float* Wp = W + (size_t)blockIdx.z * sW;
    half_t* Wtp = Wt + (size_t)blockIdx.z * sWt;
    int n0 = blockIdx.x * 32, k0 = blockIdx.y * 32;
    int tx = threadIdx.x & 31, ty = threadIdx.x >> 5;   // ty 0..7
    #pragma unroll
    for (int i = 0; i < 32; i += 8)
        t[ty + i][tx] = (n0 + tx < Nvalid) ? Wp[(size_t)(k0 + ty + i) * ldw + n0 + tx] : 0.f;
    __syncthreads();
    #pragma unroll
    for (int i = 0; i < 32; i += 8)
        Wtp[(size_t)(n0 + ty + i) * Kd + k0 + tx] = f2h(t[tx][ty + i]);
}

// ---------- fp16 MFMA GEMM: Ch[M][ldc] = A[M][Kd] * Bt[Npad][Kd]^T, fp16 out ----------
// 128x128 tile, BK=64, XOR-swizzled LDS chunks (conflict-free under the
// global_load_lds lane-contiguous constraint): physical slot p of row R holds
// global 16B-chunk p^(R&7).

#define BM 128
#define BN 128
#define BK 64

__global__ __launch_bounds__(256) void k_gemm_mfma(
    const half_t* __restrict__ A,    // [M][Kd] fp16
    const half_t* __restrict__ Bt,   // [Npad][Kd] fp16 (B transposed)
    half_t* __restrict__ C,          // fp16 output
    int Kd, int Nreal, int ldc,
    long long strideBt, long long strideC)
{
    __shared__ __align__(16) half_t As[BM * BK];
    __shared__ __align__(16) half_t Bs[BN * BK];

    const half_t* Btp = Bt + (size_t)blockIdx.z * strideBt;
    half_t* Cp = C + (size_t)blockIdx.z * strideC;
    int col0 = blockIdx.x * BN, row0 = blockIdx.y * BM;

    int lane = threadIdx.x & 63;
    int wave = threadIdx.x >> 6;
    int wm = (wave >> 1) * 64, wn = (wave & 1) * 64;

    // staging: wave covers 32 rows of each tile, 8 rows per async call.
    // lane stages row srow, physical chunk (lane&7) <- global chunk (lane&7)^(srow&7)
    int srow = wave * 32 + (lane >> 3);
    int gchunk = (lane & 7) ^ ((lane >> 3) & 7);     // (srow&7) == (lane>>3)&7
    const half_t* ga = A   + (size_t)(row0 + srow) * Kd + gchunk * 8;
    const half_t* gb = Btp + (size_t)(col0 + srow) * Kd + gchunk * 8;
    half_t* lA = &As[(wave * 32) * BK];
    half_t* lB = &Bs[(wave * 32) * BK];

    int r = lane & 15;
    int rx = r & 7;                 // (row&7) for all fragment rows this lane touches

    floatx4 acc[4][4];
    #pragma unroll
    for (int i = 0; i < 4; i++)
        #pragma unroll
        for (int j = 0; j < 4; j++) acc[i][j] = (floatx4){0.f, 0.f, 0.f, 0.f};

    for (int k0 = 0; k0 < Kd; k0 += BK) {
        #pragma unroll
        for (int j = 0; j < 4; j++) {
            async_lds16(ga + k0 + (size_t)(j * 8) * Kd, lA + (j * 8) * BK);
            async_lds16(gb + k0 + (size_t)(j * 8) * Kd, lB + (j * 8) * BK);
        }
        __syncthreads();
        #pragma unroll
        for (int kk = 0; kk < BK; kk += 32) {
            // logical chunk for this lane's 8 halves: (kk>>3) + (lane>>4)
            int phys = (((kk >> 3) + (lane >> 4)) ^ rx) << 3;
            half8 a[4], b[4];
            #pragma unroll
            for (int i = 0; i < 4; i++)
                a[i] = *(const half8*)&As[(wm + i * 16 + r) * BK + phys];
            #pragma unroll
            for (int j = 0; j < 4; j++)
                b[j] = *(const half8*)&Bs[(wn + j * 16 + r) * BK + phys];
            #pragma unroll
            for (int i = 0; i < 4; i++)
                #pragma unroll
                for (int j = 0; j < 4; j++)
                    acc[i][j] = __builtin_amdgcn_mfma_f32_16x16x32_f16(a[i], b[j], acc[i][j], 0, 0, 0);
        }
        __syncthreads();
    }

    int q4 = (lane >> 4) * 4;
    #pragma unroll
    for (int i = 0; i < 4; i++) {
        #pragma unroll
        for (int rr = 0; rr < 4; rr++) {
            int row = row0 + wm + i * 16 + q4 + rr;
            #pragma unroll
            for (int j = 0; j < 4; j++) {
                int col = col0 + wn + j * 16 + (lane & 15);
                if (col < Nreal) Cp[(size_t)row * ldc + col] = f2h(acc[i][j][rr]);
            }
        }
    }
}

// ---------- per-(node,head) attention dots (fp16 xp) ----------

__global__ void k_sd(const half_t* __restrict__ xp, const float* __restrict__ as_,
                     const float* __restrict__ ad_, float* s, float* d, int H, int C) {
    int n = blockIdx.x / H, h = blockIdx.x % H;
    int lane = threadIdx.x;
    const half_t* row = xp + (size_t)n * H * C + (size_t)h * C;
    const float* av = as_ + (size_t)h * C;
    const float* bv = ad_ + (size_t)h * C;
    float ss = 0.f, dd = 0.f;
    for (int c = lane; c < C; c += 64) {
        float x = (float)row[c];
        ss += x * av[c];
        dd += x * bv[c];
    }
    #pragma unroll
    for (int o = 32; o > 0; o >>= 1) {
        ss += __shfl_down(ss, o, 64);
        dd += __shfl_down(dd, o, 64);
    }
    if (lane == 0) { s[n * H + h] = ss; d[n * H + h] = dd; }
}

// ---------- edge softmax ----------

__global__ void k_init_mz(float* m, float* z, int n) {
    int i = blockIdx.x * 256 + threadIdx.x;
    if (i < n) { m[i] = -__builtin_inff(); z[i] = 0.f; }
}

__global__ void k_edge_max(const int* __restrict__ ei, const float* __restrict__ s,
                           const float* __restrict__ d, float* ew, float* m,
                           int H, int total) {
    int i = blockIdx.x * 256 + threadIdx.x;
    if (i >= total) return;
    int e = i / H, h = i - e * H;
    int sn, dn; get_edge(ei, e, sn, dn);
    float v = s[sn * H + h] + d[dn * H + h];
    v = (v >= 0.f) ? v : NEGS * v;   // leaky_relu
    ew[i] = v;
    atomicMaxF(&m[dn * H + h], v);
}

__global__ void k_edge_sum(const int* __restrict__ ei, float* ew,
                           const float* __restrict__ m, float* z, int H, int total) {
    int i = blockIdx.x * 256 + threadIdx.x;
    if (i >= total) return;
    int e = i / H, h = i - e * H;
    int sn, dn; get_edge(ei, e, sn, dn);
    float p = expf(ew[i] - m[dn * H + h]);
    ew[i] = p;
    atomicAdd(&z[dn * H + h], p);
}

// ---------- aggregation + ReLU + LayerNorm fused; fp16 xp in, fp16 h out ----------

__global__ __launch_bounds__(256) void k_agg_ln(
    const half_t* __restrict__ xp, const float* __restrict__ p, const float* __restrict__ z,
    const int* __restrict__ csr_src, const int* __restrict__ csr_eid,
    const int* __restrict__ rs, const float* __restrict__ bias,
    const float* __restrict__ gam, const float* __restrict__ bet,
    half_t* __restrict__ outh, int H, int C) {
    __shared__ int sh_src[256];
    __shared__ int sh_eid[256];
    __shared__ float sh_w[256 * HH];
    __shared__ float red[256];
    __shared__ float red2[256];
    int n = blockIdx.x, tid = threadIdx.x;
    int Dout = H * C;
    int NCH = Dout >> 3;             // 16B chunks per row (Dout multiple of 8)
    int CCH = C >> 3;                // chunks per head
    int start = rs[n], end = rs[n + 1];
    float acc[2][8];
    #pragma unroll
    for (int a = 0; a < 2; a++)
        #pragma unroll
        for (int e = 0; e < 8; e++) acc[a][e] = 0.f;

    for (int e0 = start; e0 < end; e0 += 256) {
        int cnt = min(256, end - e0);
        if (tid < cnt) { sh_src[tid] = csr_src[e0 + tid]; sh_eid[tid] = csr_eid[e0 + tid]; }
        __syncthreads();
        for (int i = tid; i < cnt * H; i += 256)
            sh_w[i] = p[sh_eid[i / H] * H + (i % H)];
        __syncthreads();
        int ai = 0;
        for (int ch = tid; ch < NCH; ch += 256, ai++) {
            int h = ch / CCH;
            float a0 = acc[ai][0], a1 = acc[ai][1], a2 = acc[ai][2], a3 = acc[ai][3];
            float a4 = acc[ai][4], a5 = acc[ai][5], a6 = acc[ai][6], a7 = acc[ai][7];
            for (int i = 0; i < cnt; i++) {
                float w = sh_w[i * H + h];
                half8 v = *(const half8*)(xp + (size_t)sh_src[i] * Dout + (ch << 3));
                a0 += w * (float)v[0]; a1 += w * (float)v[1];
                a2 += w * (float)v[2]; a3 += w * (float)v[3];
                a4 += w * (float)v[4]; a5 += w * (float)v[5];
                a6 += w * (float)v[6]; a7 += w * (float)v[7];
            }
            acc[ai][0] = a0; acc[ai][1] = a1; acc[ai][2] = a2; acc[ai][3] = a3;
            acc[ai][4] = a4; acc[ai][5] = a5; acc[ai][6] = a6; acc[ai][7] = a7;
        }
        __syncthreads();
    }

    // ReLU + LayerNorm in-register
    float vals[2][8];
    float sum = 0.f, sumsq = 0.f;
    int ai = 0;
    for (int ch = tid; ch < NCH; ch += 256, ai++) {
        int h = ch / CCH;
        float zi = 1.f / (z[n * H + h] + 1e-16f);
        #pragma unroll
        for (int e = 0; e < 8; e++) {
            float v = acc[ai][e] * zi + bias[(ch << 3) + e];
            v = fmaxf(v, 0.f);
            vals[ai][e] = v;
            sum += v; sumsq += v * v;
        }
    }
    red[tid] = sum; red2[tid] = sumsq;
    __syncthreads();
    for (int o = 128; o > 0; o >>= 1) {
        if (tid < o) { red[tid] += red[tid + o]; red2[tid] += red2[tid + o]; }
        __syncthreads();
    }
    float mu = red[0] / Dout;
    float var = red2[0] / Dout - mu * mu;
    float rstd = rsqrtf(var + LNEPS);
    ai = 0;
    for (int ch = tid; ch < NCH; ch += 256, ai++) {
        half8 o;
        #pragma unroll
        for (int e = 0; e < 8; e++)
            o[e] = f2h((vals[ai][e] - mu) * rstd * gam[(ch << 3) + e] + bet[(ch << 3) + e]);
        *(half8*)(outh + (size_t)n * Dout + (ch << 3)) = o;
    }
}

// ---------- head aggregation: fp16 xp in, writes per_head and idx-scattered full ----------

__global__ __launch_bounds__(256) void k_agg_head(
    const half_t* __restrict__ xp, const float* __restrict__ p, const float* __restrict__ z,
    const int* __restrict__ csr_src, const int* __restrict__ csr_eid,
    const int* __restrict__ rs, const float* __restrict__ bias,
    const int* __restrict__ idxm, float* out_full, float* out_ph) {
    __shared__ int sh_src[256];
    __shared__ int sh_eid[256];
    __shared__ float sh_w[256 * KK];
    int n = blockIdx.x, tid = threadIdx.x;
    const int Dout = KK * MM;        // 2000
    const int NCH = Dout >> 3;       // 250 chunks; threads 250..255 idle
    int start = rs[n], end = rs[n + 1];
    float acc[8];
    #pragma unroll
    for (int e = 0; e < 8; e++) acc[e] = 0.f;
    int ch = tid;                    // one chunk per thread
    int cb = ch << 3;

    for (int e0 = start; e0 < end; e0 += 256) {
        int cnt = min(256, end - e0);
        if (tid < cnt) { sh_src[tid] = csr_src[e0 + tid]; sh_eid[tid] = csr_eid[e0 + tid]; }
        __syncthreads();
        for (int i = tid; i < cnt * KK; i += 256)
            sh_w[i] = p[sh_eid[i / KK] * KK + (i % KK)];
        __syncthreads();
        if (ch < NCH) {
            for (int i = 0; i < cnt; i++) {
                const float* wv = &sh_w[i * KK];
                half8 v = *(const half8*)(xp + (size_t)sh_src[i] * Dout + cb);
                #pragma unroll
                for (int e = 0; e < 8; e++)
                    acc[e] += wv[(cb + e) / MM] * (float)v[e];
            }
        }
        __syncthreads();
    }
    if (ch < NCH) {
        #pragma unroll
        for (int e = 0; e < 8; e++) {
            int c = cb + e;
            int k = c / MM, m = c - k * MM;
            float v = acc[e] / (z[n * KK + k] + 1e-16f) + bias[c];
            out_ph[((size_t)k * NN + n) * MM + m] = v;
            out_full[(size_t)n * GG + idxm[c]] = v;
        }
    }
}

// ---------- host launcher ----------

extern "C" void kernel_launch(void* const* d_in, const int* in_sizes, int n_in,
                              void* d_out, int out_size, void* d_ws, size_t ws_size,
                              hipStream_t stream) {
    (void)in_sizes; (void)n_in; (void)out_size; (void)ws_size;
    const float* x   = (const float*)d_in[0];
    const int*   ei  = (const int*)d_in[1];
    const float* W1  = (const float*)d_in[2];
    const float* as1 = (const float*)d_in[3];
    const float* ad1 = (const float*)d_in[4];
    const float* b1  = (const float*)d_in[5];
    const float* g1  = (const float*)d_in[6];
    const float* be1 = (const float*)d_in[7];
    const float* W2  = (const float*)d_in[8];
    const float* as2 = (const float*)d_in[9];
    const float* ad2 = (const float*)d_in[10];
    const float* b2  = (const float*)d_in[11];
    const float* g2  = (const float*)d_in[12];
    const float* be2 = (const float*)d_in[13];
    const float* W3  = (const float*)d_in[14];
    const float* as3 = (const float*)d_in[15];
    const float* ad3 = (const float*)d_in[16];
    const float* b3  = (const float*)d_in[17];
    const float* g3  = (const float*)d_in[18];
    const float* be3 = (const float*)d_in[19];
    const float* Wh  = (const float*)d_in[20];
    const float* ash = (const float*)d_in[21];
    const float* adh = (const float*)d_in[22];
    const float* bh  = (const float*)d_in[23];
    const int*   idxm = (const int*)d_in[24];
    float* out = (float*)d_out;

    // workspace carve (~53 MB)
    char* w = (char*)d_ws;
    auto carve = [&](size_t bytes) { char* p = w; w += (bytes + 255) & ~(size_t)255; return p; };
    half_t* xp16    = (half_t*)carve((size_t)NN * 3584 * 2);           // GEMM output (fp16)
    half_t* Wt      = (half_t*)carve((size_t)3072 * 3584 * 2);         // transposed fp16 weights (max: W2)
    float*  sarr    = (float*)carve((size_t)NN * HH * 4);
    float*  darr    = (float*)carve((size_t)NN * HH * 4);
    float*  marr    = (float*)carve((size_t)NN * HH * 4);
    float*  zarr    = (float*)carve((size_t)NN * HH * 4);
    float*  ework   = (float*)carve((size_t)ETOT * HH * 4);
    int*    csr_src = (int*)carve((size_t)ETOT * 4);
    int*    csr_eid = (int*)carve((size_t)ETOT * 4);
    int*    rowst   = (int*)carve((size_t)(NN + 1) * 4);
    int*    cur     = (int*)carve((size_t)NN * 4);
    // fp16 activations live in d_out (29.4 MB <= 65.5 MB; dead before final writes)
    half_t* Ah = (half_t*)d_out;

    // ---- CSR build ----
    k_zero_i<<<(NN + 255) / 256, 256, 0, stream>>>(cur, NN);
    k_count<<<(ETOT + 255) / 256, 256, 0, stream>>>(ei, cur);
    k_scan<<<1, 1024, 0, stream>>>(cur, rowst, NN);
    k_zero_i<<<(NN + 255) / 256, 256, 0, stream>>>(cur, NN);
    k_fill<<<(ETOT + 255) / 256, 256, 0, stream>>>(ei, rowst, cur, csr_src, csr_eid);

    // ---- x -> fp16 ----
    k_f2h<<<(NN * 256 + 255) / 256, 256, 0, stream>>>(x, Ah, NN * 256);

    // ---- GAT layer runner (layers 1-3) ----
    auto gat = [&](const float* W, const float* as_, const float* ad_,
                   const float* bias, const float* gam, const float* bet, int Din, int C) {
        int Dout = HH * C;
        k_wt<<<dim3(Dout / 32, Din / 32, 1), 256, 0, stream>>>(W, Wt, Din, Dout, Dout, 0, 0);
        k_gemm_mfma<<<dim3(Dout / BN, NN / BM, 1), 256, 0, stream>>>(
            Ah, Wt, xp16, Din, Dout, Dout, 0, 0);
        k_sd<<<NN * HH, 64, 0, stream>>>(xp16, as_, ad_, sarr, darr, HH, C);
        k_init_mz<<<(NN * HH + 255) / 256, 256, 0, stream>>>(marr, zarr, NN * HH);
        int tot = ETOT * HH;
        k_edge_max<<<(tot + 255) / 256, 256, 0, stream>>>(ei, sarr, darr, ework, marr, HH, tot);
        k_edge_sum<<<(tot + 255) / 256, 256, 0, stream>>>(ei, ework, marr, zarr, HH, tot);
        k_agg_ln<<<NN, 256, 0, stream>>>(xp16, ework, zarr, csr_src, csr_eid, rowst,
                                         bias, gam, bet, Ah, HH, C);
    };
    gat(W1, as1, ad1, b1, g1, be1, 256,  448);
    gat(W2, as2, ad2, b2, g2, be2, 3584, 384);
    gat(W3, as3, ad3, b3, g3, be3, 3072, 256);

    // ---- head stage: K=4 single-head GATs as batched GEMM + 4-head attention ----
    k_wt<<<dim3(512 / 32, 2048 / 32, KK), 256, 0, stream>>>(
        Wh, Wt, 2048, MM, MM, (long long)2048 * MM, (long long)512 * 2048);
    k_gemm_mfma<<<dim3(512 / BN, NN / BM, KK), 256, 0, stream>>>(
        Ah, Wt, xp16, 2048, MM, GG, (long long)512 * 2048, (long long)MM);
    k_sd<<<NN * KK, 64, 0, stream>>>(xp16, ash, adh, sarr, darr, KK, MM);
    k_init_mz<<<(NN * KK + 255) / 256, 256, 0, stream>>>(marr, zarr, NN * KK);
    int tot = ETOT * KK;
    k_edge_max<<<(tot + 255) / 256, 256, 0, stream>>>(ei, sarr, darr, ework, marr, KK, tot);
    k_edge_sum<<<(tot + 255) / 256, 256, 0, stream>>>(ei, ework, marr, zarr, KK, tot);
    k_zero_f<<<(NN * GG + 255) / 256, 256, 0, stream>>>(out, NN * GG);
    k_agg_head<<<NN, 256, 0, stream>>>(xp16, ework, zarr, csr_src, csr_eid, rowst,
                                       bh, idxm, out, out + (size_t)NN * GG);
}